// Round 1
// baseline (2219.691 us; speedup 1.0000x reference)
//
#include <hip/hip_runtime.h>

// StimulusModel: per-element 256-step recurrence, FLOAT32 in/out.
//   g      = 2 * sigmoid(u - u_trigger)           (BETA=1, G_MAX=2)
//   u_next = clip(u + 0.05 - 0.1*g, 0.01, 0.2)
// Outputs concatenated: u_hist[steps][B] ++ g_hist[steps][B], f32.
//
// Write-bound: 2.147 GB of f32 stores -> ~345us floor @ 6.2 TB/s.
//
// Optimization this round: the recurrence hits an EXACT fixed point
// (clip at U_MIN) within ~6 steps for any input: once
// clip(u + 0.05 - 0.1*g(u)) == u bitwise, both u and g are constant
// for all remaining rows. Detect that wave-collectively and switch to
// a pure constant-store loop (fill-like, no compute dependency), which
// should run at fill bandwidth instead of the ~2.7 TB/s the
// compute-interleaved loop achieved. Falls back to the full 256-step
// loop if any lane never converges, so it is correct for any input.

#define VEC 4  // f32 elements per thread -> one float4 (16B) store per array per step

__global__ __launch_bounds__(256) void stimulus_kernel(
    const float* __restrict__ u_init,   // [B] f32
    const float* __restrict__ ut_p,     // [1] f32
    float* __restrict__ u_hist,         // [steps][B] f32
    float* __restrict__ g_hist,         // [steps][B] f32
    int B, int steps)
{
    const int tid = blockIdx.x * blockDim.x + threadIdx.x;
    const size_t base = (size_t)tid * VEC;
    if (base >= (size_t)B) return;

    const float ut = ut_p[0];

    float4 in = *(const float4*)(u_init + base);
    float u[VEC] = {in.x, in.y, in.z, in.w};
    float g[VEC] = {0.f, 0.f, 0.f, 0.f};

    float* up = u_hist + base;
    float* gp = g_hist + base;

    int t = 0;

    // ---- Phase 1: sequential recurrence until the whole wave reaches the
    // clip fixed point (u_next == u bitwise for all lanes & elements).
    // Once u is fixed, g = g(u) is also fixed, so every later row is a copy.
    for (; t < steps; ++t) {
        bool conv = true;
        #pragma unroll
        for (int j = 0; j < VEC; ++j) {
            // g = 2*sigmoid(u - ut) = 2 / (1 + exp(-(u - ut)))
            float e = __expf(ut - u[j]);
            g[j] = 2.0f / (1.0f + e);
            float un = u[j] + (0.05f - 0.1f * g[j]);
            un = fminf(fmaxf(un, 0.01f), 0.2f);   // clip to [U_MIN, U_MAX]
            conv = conv && (un == u[j]);          // bitwise fixed point
            u[j] = un;
        }
        *(float4*)up = make_float4(u[0], u[1], u[2], u[3]);
        *(float4*)gp = make_float4(g[0], g[1], g[2], g[3]);
        up += B;
        gp += B;
        if (__all(conv)) { ++t; break; }   // wave-uniform exit to pure-store tail
    }

    // ---- Phase 2: pure constant stores (fill-like; no compute dependency).
    const float4 uc = make_float4(u[0], u[1], u[2], u[3]);
    const float4 gc = make_float4(g[0], g[1], g[2], g[3]);
    #pragma unroll 4
    for (; t < steps; ++t) {
        *(float4*)up = uc;   // 16B coalesced store, 1KB/wave/instruction
        *(float4*)gp = gc;
        up += B;
        gp += B;
    }
}

extern "C" void kernel_launch(void* const* d_in, const int* in_sizes, int n_in,
                              void* d_out, int out_size, void* d_ws, size_t ws_size,
                              hipStream_t stream) {
    const float* u_init = (const float*)d_in[0];
    const float* ut     = (const float*)d_in[1];
    const int B = in_sizes[0];
    const int steps = out_size / (2 * B);   // out = u_hist ++ g_hist

    float* u_hist = (float*)d_out;
    float* g_hist = u_hist + (size_t)steps * (size_t)B;

    const int threads = (B + VEC - 1) / VEC;
    const int block = 256;
    const int grid = (threads + block - 1) / block;
    hipLaunchKernelGGL(stimulus_kernel, dim3(grid), dim3(block), 0, stream,
                       u_init, ut, u_hist, g_hist, B, steps);
}

// Round 2
// 2164.760 us; speedup vs baseline: 1.0254x; 1.0254x over previous
//
#include <hip/hip_runtime.h>

// StimulusModel: per-element 256-step recurrence, FLOAT32 in/out.
//   g      = 2 * sigmoid(u - u_trigger)           (BETA=1, G_MAX=2)
//   u_next = clip(u + 0.05 - 0.1*g, 0.01, 0.2)
// Outputs: u_hist[steps][B] ++ g_hist[steps][B], f32 (2.147 GB of stores).
//
// Round-1 finding: pure constant stores in the [row-strided, u/g-interleaved]
// pattern run at only ~2.7 TB/s while rocclr's contiguous fill hits 6.2 TB/s
// on the same buffer. u_hist and g_hist are exactly 2^30 bytes apart, so the
// per-wave u/g store interleave ping-pongs the same HBM channel+bank between
// two rows. Fix: prove (at runtime, from u_trigger alone) that all rows
// t >= S are the bitwise-constant scalar pair (0.01f, g(0.01f)), then write
// those rows as two contiguous single-stream grid-stride fills.
//
// Proof sketch (runtime-checked): after row 0, every column state is in
// [0.01, 0.2]. The map is monotone (du'/du in [0.95,1]) so the trajectory
// from 0.2 bounds all columns above (to within ~1e-5 of accumulated ulp
// noise). Any state u <= 0.0575 has u + 0.05 - 0.1*g(u) < 0.01, so clip
// returns the literal 0.01f exactly. Hence: if the canonical upper
// trajectory reaches <= 0.05 at step k (margin 0.0075 >> 1e-5), ALL columns
// are bitwise 0.01f from state k+1 on; rows >= k+2 are scalar for both u
// and g. If the check never triggers (other u_trigger regimes), S = steps
// and we fall back to the full sequential recurrence -> correct always.

#define VEC 4  // f32 elements per thread -> one float4 (16B) store per array per step

__device__ __forceinline__ float step_u(float u, float ut, float& g) {
    float e = __expf(ut - u);            // g = 2*sigmoid(u - ut)
    g = 2.0f / (1.0f + e);
    float un = u + (0.05f - 0.1f * g);
    return fminf(fmaxf(un, 0.01f), 0.2f);  // clip to [U_MIN, U_MAX]
}

__global__ __launch_bounds__(256) void stimulus_kernel(
    const float* __restrict__ u_init,   // [B] f32
    const float* __restrict__ ut_p,     // [1] f32
    float* __restrict__ u_hist,         // [steps][B] f32
    float* __restrict__ g_hist,         // [steps][B] f32
    int B, int steps)
{
    const int tid = blockIdx.x * blockDim.x + threadIdx.x;
    const int nthreads = gridDim.x * blockDim.x;
    const float ut = ut_p[0];

    // ---- Canonical upper-bound trajectory: find S such that all rows >= S
    // are the scalar pair (0.01f, g(0.01f)). Uniform across all threads
    // (identical deterministic arithmetic), ~6 iterations for ut=0.06.
    int S = steps;
    {
        float v = 0.2f;                  // upper bound on every column state u^1
        for (int k = 1; k < steps; ++k) {
            if (v <= 0.05f) { S = k + 2; break; }  // states >= k+1 bitwise 0.01f
            float gd; v = step_u(v, ut, gd);
        }
        if (S > steps) S = steps;
    }

    // ---- Phase A: per-column recurrence for rows [0, S). Tiny on the fast
    // path (S ~ 6 -> 48 MB); full fallback when S == steps.
    const size_t base = (size_t)tid * VEC;
    if (base < (size_t)B) {
        float4 in = *(const float4*)(u_init + base);
        float u[VEC] = {in.x, in.y, in.z, in.w};
        float g[VEC] = {0.f, 0.f, 0.f, 0.f};
        float* up = u_hist + base;
        float* gp = g_hist + base;
        int t = 0;
        for (; t < S; ++t) {
            bool conv = true;
            #pragma unroll
            for (int j = 0; j < VEC; ++j) {
                float un = step_u(u[j], ut, g[j]);
                conv = conv && (un == u[j]);     // bitwise fixed point
                u[j] = un;
            }
            *(float4*)up = make_float4(u[0], u[1], u[2], u[3]);
            *(float4*)gp = make_float4(g[0], g[1], g[2], g[3]);
            up += B; gp += B;
            // Early exit only matters on the fallback path (S == steps).
            if (S == steps && __all(conv)) { ++t; break; }
        }
        if (t < S) {  // fallback constant tail (wave-converged, S == steps)
            const float4 uc = make_float4(u[0], u[1], u[2], u[3]);
            const float4 gc = make_float4(g[0], g[1], g[2], g[3]);
            for (; t < S; ++t) {
                *(float4*)up = uc;
                *(float4*)gp = gc;
                up += B; gp += B;
            }
        }
    }

    // ---- Phase B: rows [S, steps) are scalar -> two contiguous,
    // single-stream, fill-style grid-stride writes (the 6.2 TB/s pattern).
    // Disjoint from Phase A addresses, so no inter-block ordering needed.
    if (S < steps) {
        float gk;
        step_u(0.01f, ut, gk);               // gk = g(0.01f), thread-identical
        const size_t n4 = (size_t)(steps - S) * (size_t)(B / 4);  // B % 4 == 0
        float4* ub = (float4*)(u_hist + (size_t)S * (size_t)B);
        float4* gb = (float4*)(g_hist + (size_t)S * (size_t)B);
        const float4 uc4 = make_float4(0.01f, 0.01f, 0.01f, 0.01f);
        const float4 gc4 = make_float4(gk, gk, gk, gk);
        for (size_t i = (size_t)tid; i < n4; i += (size_t)nthreads) ub[i] = uc4;
        for (size_t i = (size_t)tid; i < n4; i += (size_t)nthreads) gb[i] = gc4;
    }
}

extern "C" void kernel_launch(void* const* d_in, const int* in_sizes, int n_in,
                              void* d_out, int out_size, void* d_ws, size_t ws_size,
                              hipStream_t stream) {
    const float* u_init = (const float*)d_in[0];
    const float* ut     = (const float*)d_in[1];
    const int B = in_sizes[0];
    const int steps = out_size / (2 * B);   // out = u_hist ++ g_hist

    float* u_hist = (float*)d_out;
    float* g_hist = u_hist + (size_t)steps * (size_t)B;

    const int threads = (B + VEC - 1) / VEC;
    const int block = 256;
    const int grid = (threads + block - 1) / block;
    hipLaunchKernelGGL(stimulus_kernel, dim3(grid), dim3(block), 0, stream,
                       u_init, ut, u_hist, g_hist, B, steps);
}

// Round 4
// 2146.935 us; speedup vs baseline: 1.0339x; 1.0083x over previous
//
#include <hip/hip_runtime.h>

// StimulusModel: per-element 256-step recurrence, FLOAT32 in/out.
//   g      = 2 * sigmoid(u - u_trigger)           (BETA=1, G_MAX=2)
//   u_next = clip(u + 0.05 - 0.1*g, 0.01, 0.2)
// Outputs: u_hist[steps][B] ++ g_hist[steps][B], f32 (2.147 GB of stores).
//
// Round-3 probe (recompiled): cache-policy discrimination. All output
// stores are nontemporal (global_store_dwordx4 ... nt, L2-bypass) via a
// native ext_vector_type float4 (HIP_vector_type is rejected by
// __builtin_nontemporal_store). If L2 write-allocate thrash was the
// throttle, dur drops ~400 us; if unchanged, the kernel is already at the
// write floor and the residual is fixed harness cost (poison fill 1390 us
// + ~400 us of tiny restore dispatches).

#define VEC 4  // f32 elements per thread -> one 16B store per array per step

typedef float fx4 __attribute__((ext_vector_type(4)));

__device__ __forceinline__ float step_u(float u, float ut, float& g) {
    float e = __expf(ut - u);            // g = 2*sigmoid(u - ut)
    g = 2.0f / (1.0f + e);
    float un = u + (0.05f - 0.1f * g);
    return fminf(fmaxf(un, 0.01f), 0.2f);  // clip to [U_MIN, U_MAX]
}

__device__ __forceinline__ void nt_store4(float* p, fx4 v) {
    __builtin_nontemporal_store(v, (fx4*)p);   // global_store_dwordx4 ... nt
}

__device__ __forceinline__ fx4 mk4(float a, float b, float c, float d) {
    fx4 v; v.x = a; v.y = b; v.z = c; v.w = d; return v;
}

__global__ __launch_bounds__(256) void stimulus_kernel(
    const float* __restrict__ u_init,   // [B] f32
    const float* __restrict__ ut_p,     // [1] f32
    float* __restrict__ u_hist,         // [steps][B] f32
    float* __restrict__ g_hist,         // [steps][B] f32
    int B, int steps)
{
    const int tid = blockIdx.x * blockDim.x + threadIdx.x;
    const int nthreads = gridDim.x * blockDim.x;
    const float ut = ut_p[0];

    // ---- Canonical upper-bound trajectory: find S such that all rows >= S
    // are the scalar pair (0.01f, g(0.01f)). Thread-uniform (identical
    // deterministic arithmetic); ~6 iterations for ut=0.06. Monotone map,
    // margin 0.0075 >> accumulated ulp error; falls back to S == steps
    // (full sequential recurrence) if the check never triggers.
    int S = steps;
    {
        float v = 0.2f;                  // upper bound on every column state u^1
        for (int k = 1; k < steps; ++k) {
            if (v <= 0.05f) { S = k + 2; break; }  // states >= k+1 bitwise 0.01f
            float gd; v = step_u(v, ut, gd);
        }
        if (S > steps) S = steps;
    }

    // ---- Phase A: per-column recurrence for rows [0, S).
    const size_t base = (size_t)tid * VEC;
    if (base < (size_t)B) {
        float4 in = *(const float4*)(u_init + base);
        float u[VEC] = {in.x, in.y, in.z, in.w};
        float g[VEC] = {0.f, 0.f, 0.f, 0.f};
        float* up = u_hist + base;
        float* gp = g_hist + base;
        int t = 0;
        for (; t < S; ++t) {
            bool conv = true;
            #pragma unroll
            for (int j = 0; j < VEC; ++j) {
                float un = step_u(u[j], ut, g[j]);
                conv = conv && (un == u[j]);     // bitwise fixed point
                u[j] = un;
            }
            nt_store4(up, mk4(u[0], u[1], u[2], u[3]));
            nt_store4(gp, mk4(g[0], g[1], g[2], g[3]));
            up += B; gp += B;
            // Early exit only matters on the fallback path (S == steps).
            if (S == steps && __all(conv)) { ++t; break; }
        }
        if (t < S) {  // fallback constant tail (wave-converged, S == steps)
            const fx4 uc = mk4(u[0], u[1], u[2], u[3]);
            const fx4 gc = mk4(g[0], g[1], g[2], g[3]);
            for (; t < S; ++t) {
                nt_store4(up, uc);
                nt_store4(gp, gc);
                up += B; gp += B;
            }
        }
    }

    // ---- Phase B: rows [S, steps) are scalar -> two contiguous,
    // single-stream, fill-style grid-stride nontemporal writes.
    if (S < steps) {
        float gk;
        step_u(0.01f, ut, gk);               // gk = g(0.01f), thread-identical
        const size_t n4 = (size_t)(steps - S) * (size_t)(B / 4);  // B % 4 == 0
        float* ub = u_hist + (size_t)S * (size_t)B;
        float* gb = g_hist + (size_t)S * (size_t)B;
        const fx4 uc4 = mk4(0.01f, 0.01f, 0.01f, 0.01f);
        const fx4 gc4 = mk4(gk, gk, gk, gk);
        #pragma unroll 4
        for (size_t i = (size_t)tid; i < n4; i += (size_t)nthreads)
            nt_store4(ub + i * 4, uc4);
        #pragma unroll 4
        for (size_t i = (size_t)tid; i < n4; i += (size_t)nthreads)
            nt_store4(gb + i * 4, gc4);
    }
}

extern "C" void kernel_launch(void* const* d_in, const int* in_sizes, int n_in,
                              void* d_out, int out_size, void* d_ws, size_t ws_size,
                              hipStream_t stream) {
    const float* u_init = (const float*)d_in[0];
    const float* ut     = (const float*)d_in[1];
    const int B = in_sizes[0];
    const int steps = out_size / (2 * B);   // out = u_hist ++ g_hist

    float* u_hist = (float*)d_out;
    float* g_hist = u_hist + (size_t)steps * (size_t)B;

    const int threads = (B + VEC - 1) / VEC;
    const int block = 256;
    const int grid = (threads + block - 1) / block;
    hipLaunchKernelGGL(stimulus_kernel, dim3(grid), dim3(block), 0, stream,
                       u_init, ut, u_hist, g_hist, B, steps);
}